// Round 3
// baseline (232.675 us; speedup 1.0000x reference)
//
#include <hip/hip_runtime.h>
#include <cmath>

// ---------------------------------------------------------------------------
// DistanceAwareMultiheadAttention  (N=1536, E=49152, D=512, H=8, DH=64)
//
// Round 9:
//  - flash6_k: 4 waves / 256-thread block (one qt per wave, private LDS slab,
//    still barrier-free). Round-8 evidence: 1-wave blocks pinned at ~8
//    workgroups/CU regardless of grid size -> pack 4 waves per slot.
//  - flash6_k: delta8 gather is now exec-masked (only ~2% of (q,r) pairs
//    have an edge; unconditional max(e,0) gather was ~64 txns/load, the
//    dominant per-wave latency chain. Masked -> ~1-2 txns/load).
//  - combine grid 96 -> 384 blocks; mp2 two-stage (32 blocks + 1 block).
//  - SPLITS=8, workspace alias layout unchanged from round 8.
// ---------------------------------------------------------------------------

constexpr int Nn  = 1536;
constexpr int Dd  = 512;
constexpr int Hh  = 8;
constexpr int DHd = 64;
constexpr int SPLITS = 8;
constexpr float SCALE_F = 362.03867196751236f;   // 256*sqrt(2)
constexpr float M0 = 8.0f;                       // fixed softmax exp offset

typedef float f4 __attribute__((ext_vector_type(4)));
typedef int   i4 __attribute__((ext_vector_type(4)));
typedef __attribute__((ext_vector_type(4))) float f32x4;
typedef __attribute__((ext_vector_type(8))) short bf16x8;

__device__ inline unsigned short bf16_rne(float x) {
    unsigned u = __float_as_uint(x);
    unsigned r = u + 0x7fff + ((u >> 16) & 1);
    return (unsigned short)(r >> 16);
}
__device__ inline float bf16_tof(unsigned short h) {
    return __uint_as_float(((unsigned)h) << 16);
}

// ------------- pack feat / W into MFMA fragment order (hi/lo bf16) ----------
__global__ __launch_bounds__(256) void pack_fw_k(
    const float* __restrict__ feat,
    const float* __restrict__ Wq, const float* __restrict__ Wk, const float* __restrict__ Wv,
    unsigned short* __restrict__ pFh, unsigned short* __restrict__ pFl,
    unsigned short* __restrict__ pWh, unsigned short* __restrict__ pWl)
{
    int tg = blockIdx.x * 256 + threadIdx.x;   // 98304 per type
    int type = blockIdx.y;                     // 0 = feat, 1 = W(all 3)
    int L = tg & 63;
    int kc = (tg >> 6) & 15;
    int t10 = tg >> 10;                        // 0..95
    const float* src;
    unsigned short *oh, *ol;
    int row, col;
    if (type == 0) {
        src = feat; oh = pFh; ol = pFl;
        row = t10 * 16 + (L & 15);
        col = kc * 32 + (L >> 4) * 8;
    } else {
        int z = t10 >> 5, nt = t10 & 31;
        src = (z == 0) ? Wq : (z == 1) ? Wk : Wv;
        oh = pWh; ol = pWl;
        row = nt * 16 + (L & 15);
        col = kc * 32 + (L >> 4) * 8;
    }
    f4 a = *(const f4*)(src + (size_t)row * Dd + col);
    f4 b = *(const f4*)(src + (size_t)row * Dd + col + 4);
    float x[8];
    #pragma unroll
    for (int j = 0; j < 4; ++j) { x[j] = a[j]; x[4 + j] = b[j]; }
    unsigned short hs[8], ls[8];
    #pragma unroll
    for (int j = 0; j < 8; ++j) {
        hs[j] = bf16_rne(x[j]);
        ls[j] = bf16_rne(x[j] - bf16_tof(hs[j]));
    }
    *(bf16x8*)(oh + (size_t)tg * 8) = *(bf16x8*)hs;
    *(bf16x8*)(ol + (size_t)tg * 8) = *(bf16x8*)ls;
}

// ------------------------ QKV projection, MFMA ------------------------------
__global__ __launch_bounds__(256) void qkvm_k(
    const unsigned short* __restrict__ pFh, const unsigned short* __restrict__ pFl,
    const unsigned short* __restrict__ pWh, const unsigned short* __restrict__ pWl,
    const float* __restrict__ bq, const float* __restrict__ bk, const float* __restrict__ bv,
    float* __restrict__ Qo, float* __restrict__ Ko, float* __restrict__ Vo)
{
    // XCD-aware bijective swizzle: 576 blocks, 8 XCDs -> chunks of 72.
    const int lin = blockIdx.x + 8 * (blockIdx.y + 24 * blockIdx.z);
    const int swz = (lin & 7) * 72 + (lin >> 3);
    const int bx  = swz & 7;
    const int rem = swz >> 3;            // 0..71
    const int by  = rem % 24;
    const int bz  = rem / 24;

    const float* __restrict__ bias = (bz == 0) ? bq : (bz == 1) ? bk : bv;
    float* __restrict__ outp       = (bz == 0) ? Qo : (bz == 1) ? Ko : Vo;
    const int tid = threadIdx.x;
    const int L = tid & 63, wv = tid >> 6;
    const int l15 = L & 15, quad = L >> 4;
    const int mt0 = by * 4 + (wv & 1) * 2;
    const int nt0 = bx * 4 + (wv >> 1) * 2;

    f32x4 acc[2][2];
    #pragma unroll
    for (int i = 0; i < 2; ++i)
        #pragma unroll
        for (int j = 0; j < 2; ++j) acc[i][j] = (f32x4){0.f, 0.f, 0.f, 0.f};

    for (int kc = 0; kc < 16; ++kc) {
        bf16x8 ah[2], al[2], bh[2], bl[2];
        #pragma unroll
        for (int i = 0; i < 2; ++i) {
            size_t ao = ((size_t)((mt0 + i) * 16 + kc)) * 512 + L * 8;
            ah[i] = *(const bf16x8*)(pFh + ao);
            al[i] = *(const bf16x8*)(pFl + ao);
            size_t bo = ((size_t)((bz * 32 + nt0 + i) * 16 + kc)) * 512 + L * 8;
            bh[i] = *(const bf16x8*)(pWh + bo);
            bl[i] = *(const bf16x8*)(pWl + bo);
        }
        #pragma unroll
        for (int i = 0; i < 2; ++i)
            #pragma unroll
            for (int j = 0; j < 2; ++j) {
                f32x4 a = acc[i][j];
                a = __builtin_amdgcn_mfma_f32_16x16x32_bf16(ah[i], bh[j], a, 0, 0, 0);
                a = __builtin_amdgcn_mfma_f32_16x16x32_bf16(ah[i], bl[j], a, 0, 0, 0);
                a = __builtin_amdgcn_mfma_f32_16x16x32_bf16(al[i], bh[j], a, 0, 0, 0);
                a = __builtin_amdgcn_mfma_f32_16x16x32_bf16(al[i], bl[j], a, 0, 0, 0);
                acc[i][j] = a;
            }
    }

    #pragma unroll
    for (int i = 0; i < 2; ++i) {
        int row0 = (mt0 + i) * 16 + quad * 4;
        #pragma unroll
        for (int j = 0; j < 2; ++j) {
            int col = (nt0 + j) * 16 + l15;
            float b = bias[col];
            #pragma unroll
            for (int reg = 0; reg < 4; ++reg)
                outp[(size_t)(row0 + reg) * Dd + col] = acc[i][j][reg] + b;
        }
    }
}

// -------------------- pack Q/K/V into MFMA fragment order -------------------
__global__ __launch_bounds__(256) void pack_k(
    const float* __restrict__ Q, const float* __restrict__ K, const float* __restrict__ V,
    unsigned short* __restrict__ pQh, unsigned short* __restrict__ pQl,
    unsigned short* __restrict__ pKh, unsigned short* __restrict__ pKl,
    unsigned short* __restrict__ pVh, unsigned short* __restrict__ pVl)
{
    int tg = blockIdx.x * 256 + threadIdx.x;   // 98304 per type
    int type = blockIdx.y;
    int L = tg & 63;
    float x[8];
    unsigned short* oh;
    unsigned short* ol;
    if (type < 2) {
        const float* src = type ? K : Q;
        oh = type ? pKh : pQh;
        ol = type ? pKl : pQl;
        int kc = (tg >> 6) & 1;
        int mt = (tg >> 7) % 96;
        int h  = (tg >> 7) / 96;
        int row = mt * 16 + (L & 15);
        int col = h * 64 + kc * 32 + (L >> 4) * 8;
        f4 a = *(const f4*)(src + (size_t)row * Dd + col);
        f4 b = *(const f4*)(src + (size_t)row * Dd + col + 4);
        float sc = type ? 1.0f : 0.25f;
        #pragma unroll
        for (int j = 0; j < 4; ++j) { x[j] = a[j] * sc; x[4 + j] = b[j] * sc; }
    } else {
        oh = pVh; ol = pVl;
        int dt = (tg >> 6) & 3;
        int rc = (tg >> 8) % 48;
        int h  = (tg >> 8) / 48;
        int col  = h * 64 + dt * 16 + (L & 15);
        int row0 = rc * 32 + (L >> 4) * 8;
        #pragma unroll
        for (int j = 0; j < 8; ++j) x[j] = V[(size_t)(row0 + j) * Dd + col];
    }
    unsigned short hs[8], ls[8];
    #pragma unroll
    for (int j = 0; j < 8; ++j) {
        hs[j] = bf16_rne(x[j]);
        ls[j] = bf16_rne(x[j] - bf16_tof(hs[j]));
    }
    *(bf16x8*)(oh + (size_t)tg * 8) = *(bf16x8*)hs;
    *(bf16x8*)(ol + (size_t)tg * 8) = *(bf16x8*)ls;
}

// ------------------------- rel / eid init (vectorized) ----------------------
__global__ __launch_bounds__(256) void init_rel_k(float* __restrict__ rel, int* __restrict__ eid)
{
    size_t i = ((size_t)blockIdx.x * 256 + threadIdx.x) * 4;
    if (i < (size_t)Nn * Nn) {
        *(f4*)(rel + i) = (f4){0.f, 0.f, 0.f, 0.f};
        *(i4*)(eid + i) = (i4){-1, -1, -1, -1};
    }
}

// ----------------- scatter (with inline int64/int32 detect) -----------------
__global__ __launch_bounds__(256) void scatter_k(
    const int* __restrict__ raw, const float* __restrict__ attr,
    float* __restrict__ rel, int* __restrict__ eid, int* __restrict__ idxn, int E)
{
    int e = blockIdx.x * 256 + threadIdx.x;
    if (e >= E) return;
    int acc = 0;
    #pragma unroll
    for (int i = 0; i < 16; ++i) acc |= raw[2 * i + 1];
    int s, t;
    if (acc == 0) { s = raw[2 * e]; t = raw[2 * (E + e)]; }   // int64 low words
    else          { s = raw[e];     t = raw[E + e]; }          // plain int32
    idxn[e] = s; idxn[E + e] = t;
    size_t off = (size_t)s * Nn + t;
    atomicAdd(rel + off, attr[e] * SCALE_F);
    eid[off] = e;
}

// ------------------ odd-index sums (PE at rel==0 constants) -----------------
__global__ void oddsum_k(const float* __restrict__ Q, const float* __restrict__ K,
                         float* __restrict__ qodd, float* __restrict__ kodd,
                         float* __restrict__ koddT)
{
    int t = blockIdx.x * 256 + threadIdx.x;
    if (t >= 2 * Nn * Hh) return;
    const float* src = (t < Nn * Hh) ? Q : K;
    int i = (t < Nn * Hh) ? t : t - Nn * Hh;
    int n = i >> 3, h = i & 7;
    const float* row = src + (size_t)n * Dd + h * DHd;
    float s = 0.f;
    #pragma unroll
    for (int ii = 0; ii < 32; ++ii) s += row[2 * ii + 1];
    if (t < Nn * Hh) qodd[i] = s;
    else { kodd[i] = s; koddT[h * Nn + n] = 0.125f * s; }
}

// ------------------- per-edge, per-head logit corrections -------------------
__global__ __launch_bounds__(256) void delta_k(
    const int* __restrict__ idxn, const float* __restrict__ rel,
    const float* __restrict__ Q, const float* __restrict__ K,
    const float* __restrict__ qodd, const float* __restrict__ kodd,
    float* __restrict__ delta8, int E)
{
    int t = blockIdx.x * 256 + threadIdx.x;
    if (t >= E * Hh) return;
    int e = t >> 3, h = t & 7;
    int qi = idxn[e], ri = idxn[E + e];
    float x = rel[(size_t)qi * Nn + ri];
    const float* qrow = Q + (size_t)qi * Dd + h * DHd;
    const float* krow = K + (size_t)ri * Dd + h * DHd;
    float acc = 0.f;
    #pragma unroll
    for (int i = 0; i < 32; i += 2) {
        float d0 = expf(-0.28782313662425572f * (float)i);       // compile-time
        float d1 = expf(-0.28782313662425572f * (float)(i + 1)); // compile-time
        float s0, c0, s1, c1;
        __sincosf(x * d0, &s0, &c0);
        __sincosf(x * d1, &s1, &c1);
        f4 q4 = *(const f4*)(qrow + 2 * i);
        f4 k4 = *(const f4*)(krow + 2 * i);
        acc += (q4[0] + k4[0]) * s0 + (q4[1] + k4[1]) * c0
             + (q4[2] + k4[2]) * s1 + (q4[3] + k4[3]) * c1;
    }
    delta8[(size_t)e * Hh + h] = 0.125f * (acc - qodd[qi * Hh + h] - kodd[ri * Hh + h]);
}

// ---------------- flash attention, no-max softmax + K dbuf ------------------
// exp(logit - M0) with fixed M0: exact softmax up to a row-consistent scale
// (|logits| <~ 16, f32 exp safe to 88). No per-tile cross-lane reductions;
// row-sum reduced once after the loop. K frags double-buffered one tile ahead.
// Round 9: 4 waves / 256-thread block (wave w owns qt = qtb*4+w, private LDS
// slab, barrier-free). delta8 gather exec-masked (e>=0 on ~2% of lanes).
__global__ __launch_bounds__(256, 4) void flash6_k(
    const unsigned short* __restrict__ pQh, const unsigned short* __restrict__ pQl,
    const unsigned short* __restrict__ pKh, const unsigned short* __restrict__ pKl,
    const unsigned short* __restrict__ pVh, const unsigned short* __restrict__ pVl,
    const int* __restrict__ eid, const float* __restrict__ delta8,
    const float* __restrict__ koddT,
    float* __restrict__ Opart, float* __restrict__ Lpart)
{
    // 1536 blocks: grid (24, 8, SPLITS), x-fastest. swz = (lin%8)*192 + lin/8
    // is bijective (1536 = 8*192). XCD c gets swz [c*192,(c+1)*192) = one
    // split s, all 8 h, all 24 qtb -> per-XCD L2 working set ~3.5 MB.
    const int lin = blockIdx.x + 24 * (blockIdx.y + 8 * blockIdx.z);
    const int swz = (lin & 7) * 192 + (lin >> 3);
    const int qtb = swz % 24;
    const int hs  = swz / 24;        // 0..63
    const int h   = hs & 7;
    const int s   = hs >> 3;

    const int w   = threadIdx.x >> 6;    // wave 0..3
    const int qt  = qtb * 4 + w;
    const int L   = threadIdx.x & 63, quad = L >> 4, l15 = L & 15;
    const int q0  = qt * 16;
    __shared__ unsigned short phi[4][16][80];
    __shared__ unsigned short plo[4][16][80];

    bf16x8 qh[2], ql[2];
    #pragma unroll
    for (int kc = 0; kc < 2; ++kc) {
        size_t off = ((size_t)((h * 96 + qt) * 2 + kc)) * 512 + L * 8;
        qh[kc] = *(const bf16x8*)(pQh + off);
        ql[kc] = *(const bf16x8*)(pQl + off);
    }

    f32x4 O[4];
    float lsum[4];
    #pragma unroll
    for (int r = 0; r < 4; ++r) { lsum[r] = 0.f; O[r] = (f32x4){0.f, 0.f, 0.f, 0.f}; }

    const int NT = 24 / SPLITS;         // 3 r-tiles per split
    const int Tbase = s * NT;

    // ---- K frag double buffer: preload tile 0 ----
    bf16x8 kh0[4], kh1[4], kl0[4], kl1[4];
    {
        const int r0 = Tbase * 64;
        #pragma unroll
        for (int nt = 0; nt < 4; ++nt) {
            size_t b0 = ((size_t)((h * 96 + (r0 >> 4) + nt) * 2)) * 512 + L * 8;
            kh0[nt] = *(const bf16x8*)(pKh + b0);
            kh1[nt] = *(const bf16x8*)(pKh + b0 + 512);
            kl0[nt] = *(const bf16x8*)(pKl + b0);
            kl1[nt] = *(const bf16x8*)(pKl + b0 + 512);
        }
    }

    // ---- meta for tile 0 ----
    float kvcur[4], dcur[16];
    {
        const int r0 = Tbase * 64;
        int ecur[16];
        #pragma unroll
        for (int nt = 0; nt < 4; ++nt) {
            kvcur[nt] = koddT[h * Nn + r0 + nt * 16 + l15];
            #pragma unroll
            for (int reg = 0; reg < 4; ++reg)
                ecur[nt * 4 + reg] = eid[(size_t)(q0 + quad * 4 + reg) * Nn + r0 + nt * 16 + l15];
        }
        #pragma unroll
        for (int i = 0; i < 16; ++i) {
            int e = ecur[i];
            float d = 0.f;
            if (e >= 0) d = delta8[(size_t)e * Hh + h];   // exec-masked gather
            dcur[i] = d;
        }
    }

    for (int T = 0; T < NT; ++T) {
        const int r0 = (Tbase + T) * 64;
        const bool more = (T + 1 < NT);

        // ---- prefetch next tile's eid + koddT ----
        int   enxt[16];
        float kvnxt[4];
        if (more) {
            const int r1 = r0 + 64;
            #pragma unroll
            for (int nt = 0; nt < 4; ++nt) {
                kvnxt[nt] = koddT[h * Nn + r1 + nt * 16 + l15];
                #pragma unroll
                for (int reg = 0; reg < 4; ++reg)
                    enxt[nt * 4 + reg] = eid[(size_t)(q0 + quad * 4 + reg) * Nn + r1 + nt * 16 + l15];
            }
        }

        // ---- V loads for this tile (early issue; consumed after exp) ----
        bf16x8 vh0[4], vh1[4], vl0[4], vl1[4];
        #pragma unroll
        for (int dt = 0; dt < 4; ++dt) {
            size_t vb = ((size_t)((h * 48 + (r0 >> 5)) * 4 + dt)) * 512 + L * 8;
            vh0[dt] = *(const bf16x8*)(pVh + vb);
            vh1[dt] = *(const bf16x8*)(pVh + vb + 2048);
            vl0[dt] = *(const bf16x8*)(pVl + vb);
            vl1[dt] = *(const bf16x8*)(pVl + vb + 2048);
        }

        // ---- S = 0.25 * Q K^T from the current K buffer ----
        f32x4 S[4];
        #pragma unroll
        for (int nt = 0; nt < 4; ++nt) {
            f32x4 a = {0.f, 0.f, 0.f, 0.f};
            a = __builtin_amdgcn_mfma_f32_16x16x32_bf16(qh[0], kh0[nt], a, 0, 0, 0);
            a = __builtin_amdgcn_mfma_f32_16x16x32_bf16(qh[1], kh1[nt], a, 0, 0, 0);
            a = __builtin_amdgcn_mfma_f32_16x16x32_bf16(qh[0], kl0[nt], a, 0, 0, 0);
            a = __builtin_amdgcn_mfma_f32_16x16x32_bf16(qh[1], kl1[nt], a, 0, 0, 0);
            a = __builtin_amdgcn_mfma_f32_16x16x32_bf16(ql[0], kh0[nt], a, 0, 0, 0);
            a = __builtin_amdgcn_mfma_f32_16x16x32_bf16(ql[1], kh1[nt], a, 0, 0, 0);
            S[nt] = a;
        }

        // ---- refill K buffer for next tile (long issue->use distance) ----
        if (more) {
            const int r1 = r0 + 64;
            #pragma unroll
            for (int nt = 0; nt < 4; ++nt) {
                size_t b0 = ((size_t)((h * 96 + (r1 >> 4) + nt) * 2)) * 512 + L * 8;
                kh0[nt] = *(const bf16x8*)(pKh + b0);
                kh1[nt] = *(const bf16x8*)(pKh + b0 + 512);
                kl0[nt] = *(const bf16x8*)(pKl + b0);
                kl1[nt] = *(const bf16x8*)(pKl + b0 + 512);
            }
        }

        // ---- p = exp(logit - M0); accumulate row sums; pack to LDS ----
        #pragma unroll
        for (int reg = 0; reg < 4; ++reg) {
            float p[4];
            #pragma unroll
            for (int nt = 0; nt < 4; ++nt) {
                p[nt] = __expf(S[nt][reg] + kvcur[nt] + dcur[nt * 4 + reg] - M0);
                lsum[reg] += p[nt];
                unsigned short hi = bf16_rne(p[nt]);
                phi[w][quad * 4 + reg][nt * 16 + l15] = hi;
                plo[w][quad * 4 + reg][nt * 16 + l15] = bf16_rne(p[nt] - bf16_tof(hi));
            }
        }

        // ---- P A-frags from LDS (per-wave slab: DS in-order, no barrier) ----
        bf16x8 ph[2], pl[2];
        #pragma unroll
        for (int kc2 = 0; kc2 < 2; ++kc2) {
            ph[kc2] = *(const bf16x8*)&phi[w][l15][kc2 * 32 + quad * 8];
            pl[kc2] = *(const bf16x8*)&plo[w][l15][kc2 * 32 + quad * 8];
        }

        // ---- O += P V ----
        #pragma unroll
        for (int dt = 0; dt < 4; ++dt) {
            f32x4 a = O[dt];
            a = __builtin_amdgcn_mfma_f32_16x16x32_bf16(ph[0], vh0[dt], a, 0, 0, 0);
            a = __builtin_amdgcn_mfma_f32_16x16x32_bf16(ph[1], vh1[dt], a, 0, 0, 0);
            a = __builtin_amdgcn_mfma_f32_16x16x32_bf16(ph[0], vl0[dt], a, 0, 0, 0);
            a = __builtin_amdgcn_mfma_f32_16x16x32_bf16(ph[1], vl1[dt], a, 0, 0, 0);
            a = __builtin_amdgcn_mfma_f32_16x16x32_bf16(pl[0], vh0[dt], a, 0, 0, 0);
            a = __builtin_amdgcn_mfma_f32_16x16x32_bf16(pl[1], vh1[dt], a, 0, 0, 0);
            O[dt] = a;
        }

        // ---- gather next tile's delta (eid prefetch has landed) ----
        if (more) {
            #pragma unroll
            for (int i = 0; i < 16; ++i) {
                int e = enxt[i];
                float d = 0.f;
                if (e >= 0) d = delta8[(size_t)e * Hh + h];   // exec-masked gather
                dcur[i] = d;
            }
            #pragma unroll
            for (int nt = 0; nt < 4; ++nt) kvcur[nt] = kvnxt[nt];
        }
    }

    // ---- one deferred row-sum reduction (within each quad's 16 lanes) ----
    #pragma unroll
    for (int reg = 0; reg < 4; ++reg) {
        #pragma unroll
        for (int o = 1; o < 16; o <<= 1) lsum[reg] += __shfl_xor(lsum[reg], o);
    }

    // ---- store partials ----
    #pragma unroll
    for (int dt = 0; dt < 4; ++dt)
        #pragma unroll
        for (int reg = 0; reg < 4; ++reg)
            Opart[((size_t)(s * Hh + h) * Nn + q0 + quad * 4 + reg) * 64 + dt * 16 + l15] = O[dt][reg];
    if (l15 == 0) {
        #pragma unroll
        for (int reg = 0; reg < 4; ++reg)
            Lpart[(size_t)(s * Hh + h) * Nn + q0 + quad * 4 + reg] = lsum[reg];
    }
}

// ------------- split-K combine (plain sums) fused with maxpool s1 -----------
__global__ __launch_bounds__(256) void combine_mp_k(
    const float* __restrict__ Opart, const float* __restrict__ Lpart,
    float* __restrict__ partial)
{
    const int b = blockIdx.x;            // 384 blocks, 4 q-rows each
    const int t = threadIdx.x;
    const int cg = (t & 127) * 4;
    const int h = cg >> 6, d = cg & 63;
    const int rh = t >> 7;
    f4 mx = {-3.0e38f, -3.0e38f, -3.0e38f, -3.0e38f};
    for (int r = 0; r < 2; ++r) {
        int q = b * 4 + rh * 2 + r;
        float l = 0.f;
        f4 o = {0.f, 0.f, 0.f, 0.f};
        #pragma unroll
        for (int s2 = 0; s2 < SPLITS; ++s2) {
            l += Lpart[(size_t)(s2 * Hh + h) * Nn + q];
            f4 ov = *(const f4*)(Opart + ((size_t)(s2 * Hh + h) * Nn + q) * 64 + d);
            #pragma unroll
            for (int c = 0; c < 4; ++c) o[c] += ov[c];
        }
        float inv = 1.0f / l;
        #pragma unroll
        for (int c = 0; c < 4; ++c) mx[c] = fmaxf(mx[c], o[c] * inv);
    }
    *(f4*)(partial + (size_t)(b * 2 + rh) * 512 + cg) = mx;
}

// -------------------- two-stage final maxpool (768 -> 32 -> 1) --------------
__global__ __launch_bounds__(128) void mp2a_k(const float* __restrict__ partial,
                                              float* __restrict__ partial2)
{
    const int b = blockIdx.x;            // 32
    const int t = threadIdx.x;
    f4 mx = {-3.0e38f, -3.0e38f, -3.0e38f, -3.0e38f};
    for (int i = 0; i < 24; ++i) {
        f4 v = *(const f4*)(partial + (size_t)(b * 24 + i) * 512 + 4 * t);
        #pragma unroll
        for (int c = 0; c < 4; ++c) mx[c] = fmaxf(mx[c], v[c]);
    }
    *(f4*)(partial2 + (size_t)b * 512 + 4 * t) = mx;
}

__global__ __launch_bounds__(128) void mp2b_k(const float* __restrict__ partial2,
                                              float* __restrict__ outp)
{
    const int t = threadIdx.x;
    f4 mx = {-3.0e38f, -3.0e38f, -3.0e38f, -3.0e38f};
    for (int b = 0; b < 32; ++b) {
        f4 v = *(const f4*)(partial2 + (size_t)b * 512 + 4 * t);
        #pragma unroll
        for (int c = 0; c < 4; ++c) mx[c] = fmaxf(mx[c], v[c]);
    }
    *(f4*)(outp + 4 * t) = mx;
}

// ---------------------------------------------------------------------------
extern "C" void kernel_launch(void* const* d_in, const int* in_sizes, int n_in,
                              void* d_out, int out_size, void* d_ws, size_t ws_size,
                              hipStream_t stream)
{
    const float* feat   = (const float*)d_in[0];
    const int*   rawidx = (const int*)d_in[1];
    const float* attr   = (const float*)d_in[2];
    const float* Wq = (const float*)d_in[4];
    const float* bq = (const float*)d_in[5];
    const float* Wk = (const float*)d_in[6];
    const float* bk = (const float*)d_in[7];
    const float* Wv = (const float*)d_in[8];
    const float* bv = (const float*)d_in[9];
    float* outp = (float*)d_out;
    const int E = in_sizes[2];

    const size_t ND_ = (size_t)Nn * Dd;            // 786432
    const size_t NN_ = (size_t)Nn * Nn;            // 2359296
    const size_t PK_ = (size_t)Hh * 96 * 2 * 512;  // 786432 bf16 per pack array

    // Layout: regions dead by flash6 time come FIRST and contiguously:
    //   Q,K,V (2359296 f) | rel (2359296 f) | pFh,pFl,pWh,pWl (1572864 f-equiv)
    //   = 6291456 floats  ==  Opart at SPLITS=8 (8*8*1536*64)  -- exact alias.
    // eid (live during flash) starts right after the aliased region.
    float* ws    = (float*)d_ws;
    float* Q     = ws;                    // 786432
    float* K     = Q + ND_;               // 786432
    float* V     = K + ND_;               // 786432
    float* rel   = V + ND_;               // 2359296
    unsigned short* pFh = (unsigned short*)(rel + NN_);   // feat/W packs (dead by flash)
    unsigned short* pFl = pFh + PK_;
    unsigned short* pWh = pFl + PK_;
    unsigned short* pWl = pWh + PK_;
    int*   eid   = (int*)(pWl + PK_);     // 2359296 (LIVE during flash)
    float* delta8 = (float*)(eid + NN_);  // E*Hh = 393216
    float* qodd  = delta8 + (size_t)E * Hh;
    float* kodd  = qodd + (size_t)Nn * Hh;
    float* koddT = kodd + (size_t)Nn * Hh;
    int*   idxn  = (int*)(koddT + (size_t)Nn * Hh);
    unsigned short* pQh = (unsigned short*)(idxn + 2 * E);
    unsigned short* pQl = pQh + PK_;
    unsigned short* pKh = pQl + PK_;
    unsigned short* pKl = pKh + PK_;
    unsigned short* pVh = pKl + PK_;
    unsigned short* pVl = pVh + PK_;
    float* Lpart = (float*)(pVl + PK_);                    // SPLITS*Hh*Nn = 98304
    float* partial = Lpart + (size_t)SPLITS * Hh * Nn;     // 768*512
    float* partial2 = partial + (size_t)768 * 512;         // 32*512
    // Opart (SPLITS*Hh*Nn*64 = 6291456 floats) aliases Q,K,V + rel + pF/pW:
    // all dead by flash6 time (flash reads only pQ..pVl/eid/delta8/koddT).
    float* Opart = ws;

    pack_fw_k<<<dim3(384, 2), 256, 0, stream>>>(feat, Wq, Wk, Wv, pFh, pFl, pWh, pWl);
    qkvm_k<<<dim3(8, 24, 3), 256, 0, stream>>>(pFh, pFl, pWh, pWl, bq, bk, bv, Q, K, V);
    init_rel_k<<<(int)((NN_ / 4 + 255) / 256), 256, 0, stream>>>(rel, eid);
    scatter_k<<<(E + 255) / 256, 256, 0, stream>>>(rawidx, attr, rel, eid, idxn, E);
    oddsum_k<<<(2 * Nn * Hh + 255) / 256, 256, 0, stream>>>(Q, K, qodd, kodd, koddT);
    delta_k<<<(E * Hh + 255) / 256, 256, 0, stream>>>(idxn, rel, Q, K, qodd, kodd, delta8, E);
    pack_k<<<dim3(384, 3), 256, 0, stream>>>(Q, K, V, pQh, pQl, pKh, pKl, pVh, pVl);
    flash6_k<<<dim3(24, 8, SPLITS), 256, 0, stream>>>(pQh, pQl, pKh, pKl, pVh, pVl,
                                                      eid, delta8, koddT, Opart, Lpart);
    combine_mp_k<<<384, 256, 0, stream>>>(Opart, Lpart, partial);
    mp2a_k<<<32, 128, 0, stream>>>(partial, partial2);
    mp2b_k<<<1, 128, 0, stream>>>(partial2, outp);
}

// Round 4
// 190.969 us; speedup vs baseline: 1.2184x; 1.2184x over previous
//
#include <hip/hip_runtime.h>
#include <cmath>

// ---------------------------------------------------------------------------
// DistanceAwareMultiheadAttention  (N=1536, E=49152, D=512, H=8, DH=64)
//
// Round 10:
//  - Round 9's __launch_bounds__(256,4) forced the allocator to the 64-VGPR
//    occupancy step -> K/V fragment arrays spilled to scratch (FETCH+WRITE
//    55 -> 282 MB, flash 41 -> 84 us). The 4-wave-block occupancy mechanism
//    itself WORKED (24 -> 35%).
//  - flash6_k now __launch_bounds__(256, 2): allocator free to use its
//    natural ~84-100 VGPRs (zero spill), still 5-6 waves/SIMD resident
//    from the 1536-block grid.
//  - everything else unchanged from round 9 (4 waves/block, masked delta8
//    gather, SPLITS=8, 384-block combine, two-stage maxpool).
// ---------------------------------------------------------------------------

constexpr int Nn  = 1536;
constexpr int Dd  = 512;
constexpr int Hh  = 8;
constexpr int DHd = 64;
constexpr int SPLITS = 8;
constexpr float SCALE_F = 362.03867196751236f;   // 256*sqrt(2)
constexpr float M0 = 8.0f;                       // fixed softmax exp offset

typedef float f4 __attribute__((ext_vector_type(4)));
typedef int   i4 __attribute__((ext_vector_type(4)));
typedef __attribute__((ext_vector_type(4))) float f32x4;
typedef __attribute__((ext_vector_type(8))) short bf16x8;

__device__ inline unsigned short bf16_rne(float x) {
    unsigned u = __float_as_uint(x);
    unsigned r = u + 0x7fff + ((u >> 16) & 1);
    return (unsigned short)(r >> 16);
}
__device__ inline float bf16_tof(unsigned short h) {
    return __uint_as_float(((unsigned)h) << 16);
}

// ------------- pack feat / W into MFMA fragment order (hi/lo bf16) ----------
__global__ __launch_bounds__(256) void pack_fw_k(
    const float* __restrict__ feat,
    const float* __restrict__ Wq, const float* __restrict__ Wk, const float* __restrict__ Wv,
    unsigned short* __restrict__ pFh, unsigned short* __restrict__ pFl,
    unsigned short* __restrict__ pWh, unsigned short* __restrict__ pWl)
{
    int tg = blockIdx.x * 256 + threadIdx.x;   // 98304 per type
    int type = blockIdx.y;                     // 0 = feat, 1 = W(all 3)
    int L = tg & 63;
    int kc = (tg >> 6) & 15;
    int t10 = tg >> 10;                        // 0..95
    const float* src;
    unsigned short *oh, *ol;
    int row, col;
    if (type == 0) {
        src = feat; oh = pFh; ol = pFl;
        row = t10 * 16 + (L & 15);
        col = kc * 32 + (L >> 4) * 8;
    } else {
        int z = t10 >> 5, nt = t10 & 31;
        src = (z == 0) ? Wq : (z == 1) ? Wk : Wv;
        oh = pWh; ol = pWl;
        row = nt * 16 + (L & 15);
        col = kc * 32 + (L >> 4) * 8;
    }
    f4 a = *(const f4*)(src + (size_t)row * Dd + col);
    f4 b = *(const f4*)(src + (size_t)row * Dd + col + 4);
    float x[8];
    #pragma unroll
    for (int j = 0; j < 4; ++j) { x[j] = a[j]; x[4 + j] = b[j]; }
    unsigned short hs[8], ls[8];
    #pragma unroll
    for (int j = 0; j < 8; ++j) {
        hs[j] = bf16_rne(x[j]);
        ls[j] = bf16_rne(x[j] - bf16_tof(hs[j]));
    }
    *(bf16x8*)(oh + (size_t)tg * 8) = *(bf16x8*)hs;
    *(bf16x8*)(ol + (size_t)tg * 8) = *(bf16x8*)ls;
}

// ------------------------ QKV projection, MFMA ------------------------------
__global__ __launch_bounds__(256) void qkvm_k(
    const unsigned short* __restrict__ pFh, const unsigned short* __restrict__ pFl,
    const unsigned short* __restrict__ pWh, const unsigned short* __restrict__ pWl,
    const float* __restrict__ bq, const float* __restrict__ bk, const float* __restrict__ bv,
    float* __restrict__ Qo, float* __restrict__ Ko, float* __restrict__ Vo)
{
    // XCD-aware bijective swizzle: 576 blocks, 8 XCDs -> chunks of 72.
    const int lin = blockIdx.x + 8 * (blockIdx.y + 24 * blockIdx.z);
    const int swz = (lin & 7) * 72 + (lin >> 3);
    const int bx  = swz & 7;
    const int rem = swz >> 3;            // 0..71
    const int by  = rem % 24;
    const int bz  = rem / 24;

    const float* __restrict__ bias = (bz == 0) ? bq : (bz == 1) ? bk : bv;
    float* __restrict__ outp       = (bz == 0) ? Qo : (bz == 1) ? Ko : Vo;
    const int tid = threadIdx.x;
    const int L = tid & 63, wv = tid >> 6;
    const int l15 = L & 15, quad = L >> 4;
    const int mt0 = by * 4 + (wv & 1) * 2;
    const int nt0 = bx * 4 + (wv >> 1) * 2;

    f32x4 acc[2][2];
    #pragma unroll
    for (int i = 0; i < 2; ++i)
        #pragma unroll
        for (int j = 0; j < 2; ++j) acc[i][j] = (f32x4){0.f, 0.f, 0.f, 0.f};

    for (int kc = 0; kc < 16; ++kc) {
        bf16x8 ah[2], al[2], bh[2], bl[2];
        #pragma unroll
        for (int i = 0; i < 2; ++i) {
            size_t ao = ((size_t)((mt0 + i) * 16 + kc)) * 512 + L * 8;
            ah[i] = *(const bf16x8*)(pFh + ao);
            al[i] = *(const bf16x8*)(pFl + ao);
            size_t bo = ((size_t)((bz * 32 + nt0 + i) * 16 + kc)) * 512 + L * 8;
            bh[i] = *(const bf16x8*)(pWh + bo);
            bl[i] = *(const bf16x8*)(pWl + bo);
        }
        #pragma unroll
        for (int i = 0; i < 2; ++i)
            #pragma unroll
            for (int j = 0; j < 2; ++j) {
                f32x4 a = acc[i][j];
                a = __builtin_amdgcn_mfma_f32_16x16x32_bf16(ah[i], bh[j], a, 0, 0, 0);
                a = __builtin_amdgcn_mfma_f32_16x16x32_bf16(ah[i], bl[j], a, 0, 0, 0);
                a = __builtin_amdgcn_mfma_f32_16x16x32_bf16(al[i], bh[j], a, 0, 0, 0);
                a = __builtin_amdgcn_mfma_f32_16x16x32_bf16(al[i], bl[j], a, 0, 0, 0);
                acc[i][j] = a;
            }
    }

    #pragma unroll
    for (int i = 0; i < 2; ++i) {
        int row0 = (mt0 + i) * 16 + quad * 4;
        #pragma unroll
        for (int j = 0; j < 2; ++j) {
            int col = (nt0 + j) * 16 + l15;
            float b = bias[col];
            #pragma unroll
            for (int reg = 0; reg < 4; ++reg)
                outp[(size_t)(row0 + reg) * Dd + col] = acc[i][j][reg] + b;
        }
    }
}

// -------------------- pack Q/K/V into MFMA fragment order -------------------
__global__ __launch_bounds__(256) void pack_k(
    const float* __restrict__ Q, const float* __restrict__ K, const float* __restrict__ V,
    unsigned short* __restrict__ pQh, unsigned short* __restrict__ pQl,
    unsigned short* __restrict__ pKh, unsigned short* __restrict__ pKl,
    unsigned short* __restrict__ pVh, unsigned short* __restrict__ pVl)
{
    int tg = blockIdx.x * 256 + threadIdx.x;   // 98304 per type
    int type = blockIdx.y;
    int L = tg & 63;
    float x[8];
    unsigned short* oh;
    unsigned short* ol;
    if (type < 2) {
        const float* src = type ? K : Q;
        oh = type ? pKh : pQh;
        ol = type ? pKl : pQl;
        int kc = (tg >> 6) & 1;
        int mt = (tg >> 7) % 96;
        int h  = (tg >> 7) / 96;
        int row = mt * 16 + (L & 15);
        int col = h * 64 + kc * 32 + (L >> 4) * 8;
        f4 a = *(const f4*)(src + (size_t)row * Dd + col);
        f4 b = *(const f4*)(src + (size_t)row * Dd + col + 4);
        float sc = type ? 1.0f : 0.25f;
        #pragma unroll
        for (int j = 0; j < 4; ++j) { x[j] = a[j] * sc; x[4 + j] = b[j] * sc; }
    } else {
        oh = pVh; ol = pVl;
        int dt = (tg >> 6) & 3;
        int rc = (tg >> 8) % 48;
        int h  = (tg >> 8) / 48;
        int col  = h * 64 + dt * 16 + (L & 15);
        int row0 = rc * 32 + (L >> 4) * 8;
        #pragma unroll
        for (int j = 0; j < 8; ++j) x[j] = V[(size_t)(row0 + j) * Dd + col];
    }
    unsigned short hs[8], ls[8];
    #pragma unroll
    for (int j = 0; j < 8; ++j) {
        hs[j] = bf16_rne(x[j]);
        ls[j] = bf16_rne(x[j] - bf16_tof(hs[j]));
    }
    *(bf16x8*)(oh + (size_t)tg * 8) = *(bf16x8*)hs;
    *(bf16x8*)(ol + (size_t)tg * 8) = *(bf16x8*)ls;
}

// ------------------------- rel / eid init (vectorized) ----------------------
__global__ __launch_bounds__(256) void init_rel_k(float* __restrict__ rel, int* __restrict__ eid)
{
    size_t i = ((size_t)blockIdx.x * 256 + threadIdx.x) * 4;
    if (i < (size_t)Nn * Nn) {
        *(f4*)(rel + i) = (f4){0.f, 0.f, 0.f, 0.f};
        *(i4*)(eid + i) = (i4){-1, -1, -1, -1};
    }
}

// ----------------- scatter (with inline int64/int32 detect) -----------------
__global__ __launch_bounds__(256) void scatter_k(
    const int* __restrict__ raw, const float* __restrict__ attr,
    float* __restrict__ rel, int* __restrict__ eid, int* __restrict__ idxn, int E)
{
    int e = blockIdx.x * 256 + threadIdx.x;
    if (e >= E) return;
    int acc = 0;
    #pragma unroll
    for (int i = 0; i < 16; ++i) acc |= raw[2 * i + 1];
    int s, t;
    if (acc == 0) { s = raw[2 * e]; t = raw[2 * (E + e)]; }   // int64 low words
    else          { s = raw[e];     t = raw[E + e]; }          // plain int32
    idxn[e] = s; idxn[E + e] = t;
    size_t off = (size_t)s * Nn + t;
    atomicAdd(rel + off, attr[e] * SCALE_F);
    eid[off] = e;
}

// ------------------ odd-index sums (PE at rel==0 constants) -----------------
__global__ void oddsum_k(const float* __restrict__ Q, const float* __restrict__ K,
                         float* __restrict__ qodd, float* __restrict__ kodd,
                         float* __restrict__ koddT)
{
    int t = blockIdx.x * 256 + threadIdx.x;
    if (t >= 2 * Nn * Hh) return;
    const float* src = (t < Nn * Hh) ? Q : K;
    int i = (t < Nn * Hh) ? t : t - Nn * Hh;
    int n = i >> 3, h = i & 7;
    const float* row = src + (size_t)n * Dd + h * DHd;
    float s = 0.f;
    #pragma unroll
    for (int ii = 0; ii < 32; ++ii) s += row[2 * ii + 1];
    if (t < Nn * Hh) qodd[i] = s;
    else { kodd[i] = s; koddT[h * Nn + n] = 0.125f * s; }
}

// ------------------- per-edge, per-head logit corrections -------------------
__global__ __launch_bounds__(256) void delta_k(
    const int* __restrict__ idxn, const float* __restrict__ rel,
    const float* __restrict__ Q, const float* __restrict__ K,
    const float* __restrict__ qodd, const float* __restrict__ kodd,
    float* __restrict__ delta8, int E)
{
    int t = blockIdx.x * 256 + threadIdx.x;
    if (t >= E * Hh) return;
    int e = t >> 3, h = t & 7;
    int qi = idxn[e], ri = idxn[E + e];
    float x = rel[(size_t)qi * Nn + ri];
    const float* qrow = Q + (size_t)qi * Dd + h * DHd;
    const float* krow = K + (size_t)ri * Dd + h * DHd;
    float acc = 0.f;
    #pragma unroll
    for (int i = 0; i < 32; i += 2) {
        float d0 = expf(-0.28782313662425572f * (float)i);       // compile-time
        float d1 = expf(-0.28782313662425572f * (float)(i + 1)); // compile-time
        float s0, c0, s1, c1;
        __sincosf(x * d0, &s0, &c0);
        __sincosf(x * d1, &s1, &c1);
        f4 q4 = *(const f4*)(qrow + 2 * i);
        f4 k4 = *(const f4*)(krow + 2 * i);
        acc += (q4[0] + k4[0]) * s0 + (q4[1] + k4[1]) * c0
             + (q4[2] + k4[2]) * s1 + (q4[3] + k4[3]) * c1;
    }
    delta8[(size_t)e * Hh + h] = 0.125f * (acc - qodd[qi * Hh + h] - kodd[ri * Hh + h]);
}

// ---------------- flash attention, no-max softmax + K dbuf ------------------
// exp(logit - M0) with fixed M0: exact softmax up to a row-consistent scale
// (|logits| <~ 16, f32 exp safe to 88). No per-tile cross-lane reductions;
// row-sum reduced once after the loop. K frags double-buffered one tile ahead.
// 4 waves / 256-thread block (wave w owns qt = qtb*4+w, private LDS slab,
// barrier-free). delta8 gather exec-masked. launch_bounds(256,2): allocator
// free to ~natural VGPR count (round-9's (256,4) forced 64 VGPR -> spills).
__global__ __launch_bounds__(256, 2) void flash6_k(
    const unsigned short* __restrict__ pQh, const unsigned short* __restrict__ pQl,
    const unsigned short* __restrict__ pKh, const unsigned short* __restrict__ pKl,
    const unsigned short* __restrict__ pVh, const unsigned short* __restrict__ pVl,
    const int* __restrict__ eid, const float* __restrict__ delta8,
    const float* __restrict__ koddT,
    float* __restrict__ Opart, float* __restrict__ Lpart)
{
    // 1536 blocks: grid (24, 8, SPLITS), x-fastest. swz = (lin%8)*192 + lin/8
    // is bijective (1536 = 8*192). XCD c gets swz [c*192,(c+1)*192) = one
    // split s, all 8 h, all 24 qtb -> per-XCD L2 working set ~3.5 MB.
    const int lin = blockIdx.x + 24 * (blockIdx.y + 8 * blockIdx.z);
    const int swz = (lin & 7) * 192 + (lin >> 3);
    const int qtb = swz % 24;
    const int hs  = swz / 24;        // 0..63
    const int h   = hs & 7;
    const int s   = hs >> 3;

    const int w   = threadIdx.x >> 6;    // wave 0..3
    const int qt  = qtb * 4 + w;
    const int L   = threadIdx.x & 63, quad = L >> 4, l15 = L & 15;
    const int q0  = qt * 16;
    __shared__ unsigned short phi[4][16][80];
    __shared__ unsigned short plo[4][16][80];

    bf16x8 qh[2], ql[2];
    #pragma unroll
    for (int kc = 0; kc < 2; ++kc) {
        size_t off = ((size_t)((h * 96 + qt) * 2 + kc)) * 512 + L * 8;
        qh[kc] = *(const bf16x8*)(pQh + off);
        ql[kc] = *(const bf16x8*)(pQl + off);
    }

    f32x4 O[4];
    float lsum[4];
    #pragma unroll
    for (int r = 0; r < 4; ++r) { lsum[r] = 0.f; O[r] = (f32x4){0.f, 0.f, 0.f, 0.f}; }

    const int NT = 24 / SPLITS;         // 3 r-tiles per split
    const int Tbase = s * NT;

    // ---- K frag double buffer: preload tile 0 ----
    bf16x8 kh0[4], kh1[4], kl0[4], kl1[4];
    {
        const int r0 = Tbase * 64;
        #pragma unroll
        for (int nt = 0; nt < 4; ++nt) {
            size_t b0 = ((size_t)((h * 96 + (r0 >> 4) + nt) * 2)) * 512 + L * 8;
            kh0[nt] = *(const bf16x8*)(pKh + b0);
            kh1[nt] = *(const bf16x8*)(pKh + b0 + 512);
            kl0[nt] = *(const bf16x8*)(pKl + b0);
            kl1[nt] = *(const bf16x8*)(pKl + b0 + 512);
        }
    }

    // ---- meta for tile 0 ----
    float kvcur[4], dcur[16];
    {
        const int r0 = Tbase * 64;
        int ecur[16];
        #pragma unroll
        for (int nt = 0; nt < 4; ++nt) {
            kvcur[nt] = koddT[h * Nn + r0 + nt * 16 + l15];
            #pragma unroll
            for (int reg = 0; reg < 4; ++reg)
                ecur[nt * 4 + reg] = eid[(size_t)(q0 + quad * 4 + reg) * Nn + r0 + nt * 16 + l15];
        }
        #pragma unroll
        for (int i = 0; i < 16; ++i) {
            int e = ecur[i];
            float d = 0.f;
            if (e >= 0) d = delta8[(size_t)e * Hh + h];   // exec-masked gather
            dcur[i] = d;
        }
    }

    for (int T = 0; T < NT; ++T) {
        const int r0 = (Tbase + T) * 64;
        const bool more = (T + 1 < NT);

        // ---- prefetch next tile's eid + koddT ----
        int   enxt[16];
        float kvnxt[4];
        if (more) {
            const int r1 = r0 + 64;
            #pragma unroll
            for (int nt = 0; nt < 4; ++nt) {
                kvnxt[nt] = koddT[h * Nn + r1 + nt * 16 + l15];
                #pragma unroll
                for (int reg = 0; reg < 4; ++reg)
                    enxt[nt * 4 + reg] = eid[(size_t)(q0 + quad * 4 + reg) * Nn + r1 + nt * 16 + l15];
            }
        }

        // ---- V loads for this tile (early issue; consumed after exp) ----
        bf16x8 vh0[4], vh1[4], vl0[4], vl1[4];
        #pragma unroll
        for (int dt = 0; dt < 4; ++dt) {
            size_t vb = ((size_t)((h * 48 + (r0 >> 5)) * 4 + dt)) * 512 + L * 8;
            vh0[dt] = *(const bf16x8*)(pVh + vb);
            vh1[dt] = *(const bf16x8*)(pVh + vb + 2048);
            vl0[dt] = *(const bf16x8*)(pVl + vb);
            vl1[dt] = *(const bf16x8*)(pVl + vb + 2048);
        }

        // ---- S = 0.25 * Q K^T from the current K buffer ----
        f32x4 S[4];
        #pragma unroll
        for (int nt = 0; nt < 4; ++nt) {
            f32x4 a = {0.f, 0.f, 0.f, 0.f};
            a = __builtin_amdgcn_mfma_f32_16x16x32_bf16(qh[0], kh0[nt], a, 0, 0, 0);
            a = __builtin_amdgcn_mfma_f32_16x16x32_bf16(qh[1], kh1[nt], a, 0, 0, 0);
            a = __builtin_amdgcn_mfma_f32_16x16x32_bf16(qh[0], kl0[nt], a, 0, 0, 0);
            a = __builtin_amdgcn_mfma_f32_16x16x32_bf16(qh[1], kl1[nt], a, 0, 0, 0);
            a = __builtin_amdgcn_mfma_f32_16x16x32_bf16(ql[0], kh0[nt], a, 0, 0, 0);
            a = __builtin_amdgcn_mfma_f32_16x16x32_bf16(ql[1], kh1[nt], a, 0, 0, 0);
            S[nt] = a;
        }

        // ---- refill K buffer for next tile (long issue->use distance) ----
        if (more) {
            const int r1 = r0 + 64;
            #pragma unroll
            for (int nt = 0; nt < 4; ++nt) {
                size_t b0 = ((size_t)((h * 96 + (r1 >> 4) + nt) * 2)) * 512 + L * 8;
                kh0[nt] = *(const bf16x8*)(pKh + b0);
                kh1[nt] = *(const bf16x8*)(pKh + b0 + 512);
                kl0[nt] = *(const bf16x8*)(pKl + b0);
                kl1[nt] = *(const bf16x8*)(pKl + b0 + 512);
            }
        }

        // ---- p = exp(logit - M0); accumulate row sums; pack to LDS ----
        #pragma unroll
        for (int reg = 0; reg < 4; ++reg) {
            float p[4];
            #pragma unroll
            for (int nt = 0; nt < 4; ++nt) {
                p[nt] = __expf(S[nt][reg] + kvcur[nt] + dcur[nt * 4 + reg] - M0);
                lsum[reg] += p[nt];
                unsigned short hi = bf16_rne(p[nt]);
                phi[w][quad * 4 + reg][nt * 16 + l15] = hi;
                plo[w][quad * 4 + reg][nt * 16 + l15] = bf16_rne(p[nt] - bf16_tof(hi));
            }
        }

        // ---- P A-frags from LDS (per-wave slab: DS in-order, no barrier) ----
        bf16x8 ph[2], pl[2];
        #pragma unroll
        for (int kc2 = 0; kc2 < 2; ++kc2) {
            ph[kc2] = *(const bf16x8*)&phi[w][l15][kc2 * 32 + quad * 8];
            pl[kc2] = *(const bf16x8*)&plo[w][l15][kc2 * 32 + quad * 8];
        }

        // ---- O += P V ----
        #pragma unroll
        for (int dt = 0; dt < 4; ++dt) {
            f32x4 a = O[dt];
            a = __builtin_amdgcn_mfma_f32_16x16x32_bf16(ph[0], vh0[dt], a, 0, 0, 0);
            a = __builtin_amdgcn_mfma_f32_16x16x32_bf16(ph[1], vh1[dt], a, 0, 0, 0);
            a = __builtin_amdgcn_mfma_f32_16x16x32_bf16(ph[0], vl0[dt], a, 0, 0, 0);
            a = __builtin_amdgcn_mfma_f32_16x16x32_bf16(ph[1], vl1[dt], a, 0, 0, 0);
            a = __builtin_amdgcn_mfma_f32_16x16x32_bf16(pl[0], vh0[dt], a, 0, 0, 0);
            a = __builtin_amdgcn_mfma_f32_16x16x32_bf16(pl[1], vh1[dt], a, 0, 0, 0);
            O[dt] = a;
        }

        // ---- gather next tile's delta (eid prefetch has landed) ----
        if (more) {
            #pragma unroll
            for (int i = 0; i < 16; ++i) {
                int e = enxt[i];
                float d = 0.f;
                if (e >= 0) d = delta8[(size_t)e * Hh + h];   // exec-masked gather
                dcur[i] = d;
            }
            #pragma unroll
            for (int nt = 0; nt < 4; ++nt) kvcur[nt] = kvnxt[nt];
        }
    }

    // ---- one deferred row-sum reduction (within each quad's 16 lanes) ----
    #pragma unroll
    for (int reg = 0; reg < 4; ++reg) {
        #pragma unroll
        for (int o = 1; o < 16; o <<= 1) lsum[reg] += __shfl_xor(lsum[reg], o);
    }

    // ---- store partials ----
    #pragma unroll
    for (int dt = 0; dt < 4; ++dt)
        #pragma unroll
        for (int reg = 0; reg < 4; ++reg)
            Opart[((size_t)(s * Hh + h) * Nn + q0 + quad * 4 + reg) * 64 + dt * 16 + l15] = O[dt][reg];
    if (l15 == 0) {
        #pragma unroll
        for (int reg = 0; reg < 4; ++reg)
            Lpart[(size_t)(s * Hh + h) * Nn + q0 + quad * 4 + reg] = lsum[reg];
    }
}

// ------------- split-K combine (plain sums) fused with maxpool s1 -----------
__global__ __launch_bounds__(256) void combine_mp_k(
    const float* __restrict__ Opart, const float* __restrict__ Lpart,
    float* __restrict__ partial)
{
    const int b = blockIdx.x;            // 384 blocks, 4 q-rows each
    const int t = threadIdx.x;
    const int cg = (t & 127) * 4;
    const int h = cg >> 6, d = cg & 63;
    const int rh = t >> 7;
    f4 mx = {-3.0e38f, -3.0e38f, -3.0e38f, -3.0e38f};
    for (int r = 0; r < 2; ++r) {
        int q = b * 4 + rh * 2 + r;
        float l = 0.f;
        f4 o = {0.f, 0.f, 0.f, 0.f};
        #pragma unroll
        for (int s2 = 0; s2 < SPLITS; ++s2) {
            l += Lpart[(size_t)(s2 * Hh + h) * Nn + q];
            f4 ov = *(const f4*)(Opart + ((size_t)(s2 * Hh + h) * Nn + q) * 64 + d);
            #pragma unroll
            for (int c = 0; c < 4; ++c) o[c] += ov[c];
        }
        float inv = 1.0f / l;
        #pragma unroll
        for (int c = 0; c < 4; ++c) mx[c] = fmaxf(mx[c], o[c] * inv);
    }
    *(f4*)(partial + (size_t)(b * 2 + rh) * 512 + cg) = mx;
}

// -------------------- two-stage final maxpool (768 -> 32 -> 1) --------------
__global__ __launch_bounds__(128) void mp2a_k(const float* __restrict__ partial,
                                              float* __restrict__ partial2)
{
    const int b = blockIdx.x;            // 32
    const int t = threadIdx.x;
    f4 mx = {-3.0e38f, -3.0e38f, -3.0e38f, -3.0e38f};
    for (int i = 0; i < 24; ++i) {
        f4 v = *(const f4*)(partial + (size_t)(b * 24 + i) * 512 + 4 * t);
        #pragma unroll
        for (int c = 0; c < 4; ++c) mx[c] = fmaxf(mx[c], v[c]);
    }
    *(f4*)(partial2 + (size_t)b * 512 + 4 * t) = mx;
}

__global__ __launch_bounds__(128) void mp2b_k(const float* __restrict__ partial2,
                                              float* __restrict__ outp)
{
    const int t = threadIdx.x;
    f4 mx = {-3.0e38f, -3.0e38f, -3.0e38f, -3.0e38f};
    for (int b = 0; b < 32; ++b) {
        f4 v = *(const f4*)(partial2 + (size_t)b * 512 + 4 * t);
        #pragma unroll
        for (int c = 0; c < 4; ++c) mx[c] = fmaxf(mx[c], v[c]);
    }
    *(f4*)(outp + 4 * t) = mx;
}

// ---------------------------------------------------------------------------
extern "C" void kernel_launch(void* const* d_in, const int* in_sizes, int n_in,
                              void* d_out, int out_size, void* d_ws, size_t ws_size,
                              hipStream_t stream)
{
    const float* feat   = (const float*)d_in[0];
    const int*   rawidx = (const int*)d_in[1];
    const float* attr   = (const float*)d_in[2];
    const float* Wq = (const float*)d_in[4];
    const float* bq = (const float*)d_in[5];
    const float* Wk = (const float*)d_in[6];
    const float* bk = (const float*)d_in[7];
    const float* Wv = (const float*)d_in[8];
    const float* bv = (const float*)d_in[9];
    float* outp = (float*)d_out;
    const int E = in_sizes[2];

    const size_t ND_ = (size_t)Nn * Dd;            // 786432
    const size_t NN_ = (size_t)Nn * Nn;            // 2359296
    const size_t PK_ = (size_t)Hh * 96 * 2 * 512;  // 786432 bf16 per pack array

    // Layout: regions dead by flash6 time come FIRST and contiguously:
    //   Q,K,V (2359296 f) | rel (2359296 f) | pFh,pFl,pWh,pWl (1572864 f-equiv)
    //   = 6291456 floats  ==  Opart at SPLITS=8 (8*8*1536*64)  -- exact alias.
    // eid (live during flash) starts right after the aliased region.
    float* ws    = (float*)d_ws;
    float* Q     = ws;                    // 786432
    float* K     = Q + ND_;               // 786432
    float* V     = K + ND_;               // 786432
    float* rel   = V + ND_;               // 2359296
    unsigned short* pFh = (unsigned short*)(rel + NN_);   // feat/W packs (dead by flash)
    unsigned short* pFl = pFh + PK_;
    unsigned short* pWh = pFl + PK_;
    unsigned short* pWl = pWh + PK_;
    int*   eid   = (int*)(pWl + PK_);     // 2359296 (LIVE during flash)
    float* delta8 = (float*)(eid + NN_);  // E*Hh = 393216
    float* qodd  = delta8 + (size_t)E * Hh;
    float* kodd  = qodd + (size_t)Nn * Hh;
    float* koddT = kodd + (size_t)Nn * Hh;
    int*   idxn  = (int*)(koddT + (size_t)Nn * Hh);
    unsigned short* pQh = (unsigned short*)(idxn + 2 * E);
    unsigned short* pQl = pQh + PK_;
    unsigned short* pKh = pQl + PK_;
    unsigned short* pKl = pKh + PK_;
    unsigned short* pVh = pKl + PK_;
    unsigned short* pVl = pVh + PK_;
    float* Lpart = (float*)(pVl + PK_);                    // SPLITS*Hh*Nn = 98304
    float* partial = Lpart + (size_t)SPLITS * Hh * Nn;     // 768*512
    float* partial2 = partial + (size_t)768 * 512;         // 32*512
    // Opart (SPLITS*Hh*Nn*64 = 6291456 floats) aliases Q,K,V + rel + pF/pW:
    // all dead by flash6 time (flash reads only pQ..pVl/eid/delta8/koddT).
    float* Opart = ws;

    pack_fw_k<<<dim3(384, 2), 256, 0, stream>>>(feat, Wq, Wk, Wv, pFh, pFl, pWh, pWl);
    qkvm_k<<<dim3(8, 24, 3), 256, 0, stream>>>(pFh, pFl, pWh, pWl, bq, bk, bv, Q, K, V);
    init_rel_k<<<(int)((NN_ / 4 + 255) / 256), 256, 0, stream>>>(rel, eid);
    scatter_k<<<(E + 255) / 256, 256, 0, stream>>>(rawidx, attr, rel, eid, idxn, E);
    oddsum_k<<<(2 * Nn * Hh + 255) / 256, 256, 0, stream>>>(Q, K, qodd, kodd, koddT);
    delta_k<<<(E * Hh + 255) / 256, 256, 0, stream>>>(idxn, rel, Q, K, qodd, kodd, delta8, E);
    pack_k<<<dim3(384, 3), 256, 0, stream>>>(Q, K, V, pQh, pQl, pKh, pKl, pVh, pVl);
    flash6_k<<<dim3(24, 8, SPLITS), 256, 0, stream>>>(pQh, pQl, pKh, pKl, pVh, pVl,
                                                      eid, delta8, koddT, Opart, Lpart);
    combine_mp_k<<<384, 256, 0, stream>>>(Opart, Lpart, partial);
    mp2a_k<<<32, 128, 0, stream>>>(partial, partial2);
    mp2b_k<<<1, 128, 0, stream>>>(partial2, outp);
}

// Round 6
// 184.525 us; speedup vs baseline: 1.2609x; 1.0349x over previous
//
#include <hip/hip_runtime.h>
#include <cmath>

// ---------------------------------------------------------------------------
// DistanceAwareMultiheadAttention  (N=1536, E=49152, D=512, H=8, DH=64)
//
// Round 12 (= round 11 with the __exp2f -> __expf build fix):
//  - delta_k rewritten as delta2_k: one WAVE per edge (was one thread per
//    (edge,head)). Old layout: every f4 load = 64-way diverged gather
//    (8 random rows x 8 head-offsets), ~12.6M 16B txns total, txn-rate
//    bound (~20us). New: lane j = dim-within-head, loop h -> coalesced
//    256B row reads; trig factor computed ONCE per lane (shared across
//    heads, 4x fewer transcendentals); 6-level shfl_xor butterfly per head.
//  - everything else unchanged from round 10 (flash6 4-wave blocks,
//    launch_bounds(256,2), masked delta8 gather, SPLITS=8).
// ---------------------------------------------------------------------------

constexpr int Nn  = 1536;
constexpr int Dd  = 512;
constexpr int Hh  = 8;
constexpr int DHd = 64;
constexpr int SPLITS = 8;
constexpr float SCALE_F = 362.03867196751236f;   // 256*sqrt(2)
constexpr float M0 = 8.0f;                       // fixed softmax exp offset

typedef float f4 __attribute__((ext_vector_type(4)));
typedef int   i4 __attribute__((ext_vector_type(4)));
typedef __attribute__((ext_vector_type(4))) float f32x4;
typedef __attribute__((ext_vector_type(8))) short bf16x8;

__device__ inline unsigned short bf16_rne(float x) {
    unsigned u = __float_as_uint(x);
    unsigned r = u + 0x7fff + ((u >> 16) & 1);
    return (unsigned short)(r >> 16);
}
__device__ inline float bf16_tof(unsigned short h) {
    return __uint_as_float(((unsigned)h) << 16);
}

// ------------- pack feat / W into MFMA fragment order (hi/lo bf16) ----------
__global__ __launch_bounds__(256) void pack_fw_k(
    const float* __restrict__ feat,
    const float* __restrict__ Wq, const float* __restrict__ Wk, const float* __restrict__ Wv,
    unsigned short* __restrict__ pFh, unsigned short* __restrict__ pFl,
    unsigned short* __restrict__ pWh, unsigned short* __restrict__ pWl)
{
    int tg = blockIdx.x * 256 + threadIdx.x;   // 98304 per type
    int type = blockIdx.y;                     // 0 = feat, 1 = W(all 3)
    int L = tg & 63;
    int kc = (tg >> 6) & 15;
    int t10 = tg >> 10;                        // 0..95
    const float* src;
    unsigned short *oh, *ol;
    int row, col;
    if (type == 0) {
        src = feat; oh = pFh; ol = pFl;
        row = t10 * 16 + (L & 15);
        col = kc * 32 + (L >> 4) * 8;
    } else {
        int z = t10 >> 5, nt = t10 & 31;
        src = (z == 0) ? Wq : (z == 1) ? Wk : Wv;
        oh = pWh; ol = pWl;
        row = nt * 16 + (L & 15);
        col = kc * 32 + (L >> 4) * 8;
    }
    f4 a = *(const f4*)(src + (size_t)row * Dd + col);
    f4 b = *(const f4*)(src + (size_t)row * Dd + col + 4);
    float x[8];
    #pragma unroll
    for (int j = 0; j < 4; ++j) { x[j] = a[j]; x[4 + j] = b[j]; }
    unsigned short hs[8], ls[8];
    #pragma unroll
    for (int j = 0; j < 8; ++j) {
        hs[j] = bf16_rne(x[j]);
        ls[j] = bf16_rne(x[j] - bf16_tof(hs[j]));
    }
    *(bf16x8*)(oh + (size_t)tg * 8) = *(bf16x8*)hs;
    *(bf16x8*)(ol + (size_t)tg * 8) = *(bf16x8*)ls;
}

// ------------------------ QKV projection, MFMA ------------------------------
__global__ __launch_bounds__(256) void qkvm_k(
    const unsigned short* __restrict__ pFh, const unsigned short* __restrict__ pFl,
    const unsigned short* __restrict__ pWh, const unsigned short* __restrict__ pWl,
    const float* __restrict__ bq, const float* __restrict__ bk, const float* __restrict__ bv,
    float* __restrict__ Qo, float* __restrict__ Ko, float* __restrict__ Vo)
{
    // XCD-aware bijective swizzle: 576 blocks, 8 XCDs -> chunks of 72.
    const int lin = blockIdx.x + 8 * (blockIdx.y + 24 * blockIdx.z);
    const int swz = (lin & 7) * 72 + (lin >> 3);
    const int bx  = swz & 7;
    const int rem = swz >> 3;            // 0..71
    const int by  = rem % 24;
    const int bz  = rem / 24;

    const float* __restrict__ bias = (bz == 0) ? bq : (bz == 1) ? bk : bv;
    float* __restrict__ outp       = (bz == 0) ? Qo : (bz == 1) ? Ko : Vo;
    const int tid = threadIdx.x;
    const int L = tid & 63, wv = tid >> 6;
    const int l15 = L & 15, quad = L >> 4;
    const int mt0 = by * 4 + (wv & 1) * 2;
    const int nt0 = bx * 4 + (wv >> 1) * 2;

    f32x4 acc[2][2];
    #pragma unroll
    for (int i = 0; i < 2; ++i)
        #pragma unroll
        for (int j = 0; j < 2; ++j) acc[i][j] = (f32x4){0.f, 0.f, 0.f, 0.f};

    for (int kc = 0; kc < 16; ++kc) {
        bf16x8 ah[2], al[2], bh[2], bl[2];
        #pragma unroll
        for (int i = 0; i < 2; ++i) {
            size_t ao = ((size_t)((mt0 + i) * 16 + kc)) * 512 + L * 8;
            ah[i] = *(const bf16x8*)(pFh + ao);
            al[i] = *(const bf16x8*)(pFl + ao);
            size_t bo = ((size_t)((bz * 32 + nt0 + i) * 16 + kc)) * 512 + L * 8;
            bh[i] = *(const bf16x8*)(pWh + bo);
            bl[i] = *(const bf16x8*)(pWl + bo);
        }
        #pragma unroll
        for (int i = 0; i < 2; ++i)
            #pragma unroll
            for (int j = 0; j < 2; ++j) {
                f32x4 a = acc[i][j];
                a = __builtin_amdgcn_mfma_f32_16x16x32_bf16(ah[i], bh[j], a, 0, 0, 0);
                a = __builtin_amdgcn_mfma_f32_16x16x32_bf16(ah[i], bl[j], a, 0, 0, 0);
                a = __builtin_amdgcn_mfma_f32_16x16x32_bf16(al[i], bh[j], a, 0, 0, 0);
                a = __builtin_amdgcn_mfma_f32_16x16x32_bf16(al[i], bl[j], a, 0, 0, 0);
                acc[i][j] = a;
            }
    }

    #pragma unroll
    for (int i = 0; i < 2; ++i) {
        int row0 = (mt0 + i) * 16 + quad * 4;
        #pragma unroll
        for (int j = 0; j < 2; ++j) {
            int col = (nt0 + j) * 16 + l15;
            float b = bias[col];
            #pragma unroll
            for (int reg = 0; reg < 4; ++reg)
                outp[(size_t)(row0 + reg) * Dd + col] = acc[i][j][reg] + b;
        }
    }
}

// -------------------- pack Q/K/V into MFMA fragment order -------------------
__global__ __launch_bounds__(256) void pack_k(
    const float* __restrict__ Q, const float* __restrict__ K, const float* __restrict__ V,
    unsigned short* __restrict__ pQh, unsigned short* __restrict__ pQl,
    unsigned short* __restrict__ pKh, unsigned short* __restrict__ pKl,
    unsigned short* __restrict__ pVh, unsigned short* __restrict__ pVl)
{
    int tg = blockIdx.x * 256 + threadIdx.x;   // 98304 per type
    int type = blockIdx.y;
    int L = tg & 63;
    float x[8];
    unsigned short* oh;
    unsigned short* ol;
    if (type < 2) {
        const float* src = type ? K : Q;
        oh = type ? pKh : pQh;
        ol = type ? pKl : pQl;
        int kc = (tg >> 6) & 1;
        int mt = (tg >> 7) % 96;
        int h  = (tg >> 7) / 96;
        int row = mt * 16 + (L & 15);
        int col = h * 64 + kc * 32 + (L >> 4) * 8;
        f4 a = *(const f4*)(src + (size_t)row * Dd + col);
        f4 b = *(const f4*)(src + (size_t)row * Dd + col + 4);
        float sc = type ? 1.0f : 0.25f;
        #pragma unroll
        for (int j = 0; j < 4; ++j) { x[j] = a[j] * sc; x[4 + j] = b[j] * sc; }
    } else {
        oh = pVh; ol = pVl;
        int dt = (tg >> 6) & 3;
        int rc = (tg >> 8) % 48;
        int h  = (tg >> 8) / 48;
        int col  = h * 64 + dt * 16 + (L & 15);
        int row0 = rc * 32 + (L >> 4) * 8;
        #pragma unroll
        for (int j = 0; j < 8; ++j) x[j] = V[(size_t)(row0 + j) * Dd + col];
    }
    unsigned short hs[8], ls[8];
    #pragma unroll
    for (int j = 0; j < 8; ++j) {
        hs[j] = bf16_rne(x[j]);
        ls[j] = bf16_rne(x[j] - bf16_tof(hs[j]));
    }
    *(bf16x8*)(oh + (size_t)tg * 8) = *(bf16x8*)hs;
    *(bf16x8*)(ol + (size_t)tg * 8) = *(bf16x8*)ls;
}

// ------------------------- rel / eid init (vectorized) ----------------------
__global__ __launch_bounds__(256) void init_rel_k(float* __restrict__ rel, int* __restrict__ eid)
{
    size_t i = ((size_t)blockIdx.x * 256 + threadIdx.x) * 4;
    if (i < (size_t)Nn * Nn) {
        *(f4*)(rel + i) = (f4){0.f, 0.f, 0.f, 0.f};
        *(i4*)(eid + i) = (i4){-1, -1, -1, -1};
    }
}

// ----------------- scatter (with inline int64/int32 detect) -----------------
__global__ __launch_bounds__(256) void scatter_k(
    const int* __restrict__ raw, const float* __restrict__ attr,
    float* __restrict__ rel, int* __restrict__ eid, int* __restrict__ idxn, int E)
{
    int e = blockIdx.x * 256 + threadIdx.x;
    if (e >= E) return;
    int acc = 0;
    #pragma unroll
    for (int i = 0; i < 16; ++i) acc |= raw[2 * i + 1];
    int s, t;
    if (acc == 0) { s = raw[2 * e]; t = raw[2 * (E + e)]; }   // int64 low words
    else          { s = raw[e];     t = raw[E + e]; }          // plain int32
    idxn[e] = s; idxn[E + e] = t;
    size_t off = (size_t)s * Nn + t;
    atomicAdd(rel + off, attr[e] * SCALE_F);
    eid[off] = e;
}

// ------------------ odd-index sums (PE at rel==0 constants) -----------------
__global__ void oddsum_k(const float* __restrict__ Q, const float* __restrict__ K,
                         float* __restrict__ qodd, float* __restrict__ kodd,
                         float* __restrict__ koddT)
{
    int t = blockIdx.x * 256 + threadIdx.x;
    if (t >= 2 * Nn * Hh) return;
    const float* src = (t < Nn * Hh) ? Q : K;
    int i = (t < Nn * Hh) ? t : t - Nn * Hh;
    int n = i >> 3, h = i & 7;
    const float* row = src + (size_t)n * Dd + h * DHd;
    float s = 0.f;
    #pragma unroll
    for (int ii = 0; ii < 32; ++ii) s += row[2 * ii + 1];
    if (t < Nn * Hh) qodd[i] = s;
    else { kodd[i] = s; koddT[h * Nn + n] = 0.125f * s; }
}

// ------------------- per-edge, per-head logit corrections -------------------
// Round 12: one WAVE per edge. Lane j = dim-within-head; trig factor t_j
// computed once per lane (identical for all 8 heads); Q/K row reads are
// coalesced 256B wave transactions; per-head sum via shfl_xor butterfly.
__global__ __launch_bounds__(256) void delta2_k(
    const int* __restrict__ idxn, const float* __restrict__ rel,
    const float* __restrict__ Q, const float* __restrict__ K,
    const float* __restrict__ qodd, const float* __restrict__ kodd,
    float* __restrict__ delta8, int E)
{
    const int w = threadIdx.x >> 6;          // wave in block
    const int e = blockIdx.x * 4 + w;
    if (e >= E) return;
    const int j = threadIdx.x & 63;          // dim within head
    const int qi = idxn[e], ri = idxn[E + e];
    const float x = rel[(size_t)qi * Nn + ri];
    // div[m] = exp(-m*ln(1e4)/32), m = j>>1  (same constant as ref)
    const float dj = __expf(-0.28782313662425572f * (float)(j >> 1));
    float sj, cj;
    __sincosf(x * dj, &sj, &cj);
    const float tj = (j & 1) ? cj : sj;      // interleaved sin/cos PE
    const float* qrow = Q + (size_t)qi * Dd;
    const float* krow = K + (size_t)ri * Dd;
    float out = 0.f;
    #pragma unroll
    for (int h = 0; h < 8; ++h) {
        float v = (qrow[h * 64 + j] + krow[h * 64 + j]) * tj;
        #pragma unroll
        for (int o = 1; o < 64; o <<= 1) v += __shfl_xor(v, o);
        if (j == h) out = v;                 // compile-time h: cndmask, no scratch
    }
    if (j < 8)
        delta8[(size_t)e * Hh + j] = 0.125f * (out - qodd[qi * Hh + j] - kodd[ri * Hh + j]);
}

// ---------------- flash attention, no-max softmax + K dbuf ------------------
// exp(logit - M0) with fixed M0: exact softmax up to a row-consistent scale
// (|logits| <~ 16, f32 exp safe to 88). No per-tile cross-lane reductions;
// row-sum reduced once after the loop. K frags double-buffered one tile ahead.
// 4 waves / 256-thread block (wave w owns qt = qtb*4+w, private LDS slab,
// barrier-free). delta8 gather exec-masked. launch_bounds(256,2): allocator
// free to ~natural VGPR count (round-9's (256,4) forced 64 VGPR -> spills).
__global__ __launch_bounds__(256, 2) void flash6_k(
    const unsigned short* __restrict__ pQh, const unsigned short* __restrict__ pQl,
    const unsigned short* __restrict__ pKh, const unsigned short* __restrict__ pKl,
    const unsigned short* __restrict__ pVh, const unsigned short* __restrict__ pVl,
    const int* __restrict__ eid, const float* __restrict__ delta8,
    const float* __restrict__ koddT,
    float* __restrict__ Opart, float* __restrict__ Lpart)
{
    // 1536 blocks: grid (24, 8, SPLITS), x-fastest. swz = (lin%8)*192 + lin/8
    // is bijective (1536 = 8*192). XCD c gets swz [c*192,(c+1)*192) = one
    // split s, all 8 h, all 24 qtb -> per-XCD L2 working set ~3.5 MB.
    const int lin = blockIdx.x + 24 * (blockIdx.y + 8 * blockIdx.z);
    const int swz = (lin & 7) * 192 + (lin >> 3);
    const int qtb = swz % 24;
    const int hs  = swz / 24;        // 0..63
    const int h   = hs & 7;
    const int s   = hs >> 3;

    const int w   = threadIdx.x >> 6;    // wave 0..3
    const int qt  = qtb * 4 + w;
    const int L   = threadIdx.x & 63, quad = L >> 4, l15 = L & 15;
    const int q0  = qt * 16;
    __shared__ unsigned short phi[4][16][80];
    __shared__ unsigned short plo[4][16][80];

    bf16x8 qh[2], ql[2];
    #pragma unroll
    for (int kc = 0; kc < 2; ++kc) {
        size_t off = ((size_t)((h * 96 + qt) * 2 + kc)) * 512 + L * 8;
        qh[kc] = *(const bf16x8*)(pQh + off);
        ql[kc] = *(const bf16x8*)(pQl + off);
    }

    f32x4 O[4];
    float lsum[4];
    #pragma unroll
    for (int r = 0; r < 4; ++r) { lsum[r] = 0.f; O[r] = (f32x4){0.f, 0.f, 0.f, 0.f}; }

    const int NT = 24 / SPLITS;         // 3 r-tiles per split
    const int Tbase = s * NT;

    // ---- K frag double buffer: preload tile 0 ----
    bf16x8 kh0[4], kh1[4], kl0[4], kl1[4];
    {
        const int r0 = Tbase * 64;
        #pragma unroll
        for (int nt = 0; nt < 4; ++nt) {
            size_t b0 = ((size_t)((h * 96 + (r0 >> 4) + nt) * 2)) * 512 + L * 8;
            kh0[nt] = *(const bf16x8*)(pKh + b0);
            kh1[nt] = *(const bf16x8*)(pKh + b0 + 512);
            kl0[nt] = *(const bf16x8*)(pKl + b0);
            kl1[nt] = *(const bf16x8*)(pKl + b0 + 512);
        }
    }

    // ---- meta for tile 0 ----
    float kvcur[4], dcur[16];
    {
        const int r0 = Tbase * 64;
        int ecur[16];
        #pragma unroll
        for (int nt = 0; nt < 4; ++nt) {
            kvcur[nt] = koddT[h * Nn + r0 + nt * 16 + l15];
            #pragma unroll
            for (int reg = 0; reg < 4; ++reg)
                ecur[nt * 4 + reg] = eid[(size_t)(q0 + quad * 4 + reg) * Nn + r0 + nt * 16 + l15];
        }
        #pragma unroll
        for (int i = 0; i < 16; ++i) {
            int e = ecur[i];
            float d = 0.f;
            if (e >= 0) d = delta8[(size_t)e * Hh + h];   // exec-masked gather
            dcur[i] = d;
        }
    }

    for (int T = 0; T < NT; ++T) {
        const int r0 = (Tbase + T) * 64;
        const bool more = (T + 1 < NT);

        // ---- prefetch next tile's eid + koddT ----
        int   enxt[16];
        float kvnxt[4];
        if (more) {
            const int r1 = r0 + 64;
            #pragma unroll
            for (int nt = 0; nt < 4; ++nt) {
                kvnxt[nt] = koddT[h * Nn + r1 + nt * 16 + l15];
                #pragma unroll
                for (int reg = 0; reg < 4; ++reg)
                    enxt[nt * 4 + reg] = eid[(size_t)(q0 + quad * 4 + reg) * Nn + r1 + nt * 16 + l15];
            }
        }

        // ---- V loads for this tile (early issue; consumed after exp) ----
        bf16x8 vh0[4], vh1[4], vl0[4], vl1[4];
        #pragma unroll
        for (int dt = 0; dt < 4; ++dt) {
            size_t vb = ((size_t)((h * 48 + (r0 >> 5)) * 4 + dt)) * 512 + L * 8;
            vh0[dt] = *(const bf16x8*)(pVh + vb);
            vh1[dt] = *(const bf16x8*)(pVh + vb + 2048);
            vl0[dt] = *(const bf16x8*)(pVl + vb);
            vl1[dt] = *(const bf16x8*)(pVl + vb + 2048);
        }

        // ---- S = 0.25 * Q K^T from the current K buffer ----
        f32x4 S[4];
        #pragma unroll
        for (int nt = 0; nt < 4; ++nt) {
            f32x4 a = {0.f, 0.f, 0.f, 0.f};
            a = __builtin_amdgcn_mfma_f32_16x16x32_bf16(qh[0], kh0[nt], a, 0, 0, 0);
            a = __builtin_amdgcn_mfma_f32_16x16x32_bf16(qh[1], kh1[nt], a, 0, 0, 0);
            a = __builtin_amdgcn_mfma_f32_16x16x32_bf16(qh[0], kl0[nt], a, 0, 0, 0);
            a = __builtin_amdgcn_mfma_f32_16x16x32_bf16(qh[1], kl1[nt], a, 0, 0, 0);
            a = __builtin_amdgcn_mfma_f32_16x16x32_bf16(ql[0], kh0[nt], a, 0, 0, 0);
            a = __builtin_amdgcn_mfma_f32_16x16x32_bf16(ql[1], kh1[nt], a, 0, 0, 0);
            S[nt] = a;
        }

        // ---- refill K buffer for next tile (long issue->use distance) ----
        if (more) {
            const int r1 = r0 + 64;
            #pragma unroll
            for (int nt = 0; nt < 4; ++nt) {
                size_t b0 = ((size_t)((h * 96 + (r1 >> 4) + nt) * 2)) * 512 + L * 8;
                kh0[nt] = *(const bf16x8*)(pKh + b0);
                kh1[nt] = *(const bf16x8*)(pKh + b0 + 512);
                kl0[nt] = *(const bf16x8*)(pKl + b0);
                kl1[nt] = *(const bf16x8*)(pKl + b0 + 512);
            }
        }

        // ---- p = exp(logit - M0); accumulate row sums; pack to LDS ----
        #pragma unroll
        for (int reg = 0; reg < 4; ++reg) {
            float p[4];
            #pragma unroll
            for (int nt = 0; nt < 4; ++nt) {
                p[nt] = __expf(S[nt][reg] + kvcur[nt] + dcur[nt * 4 + reg] - M0);
                lsum[reg] += p[nt];
                unsigned short hi = bf16_rne(p[nt]);
                phi[w][quad * 4 + reg][nt * 16 + l15] = hi;
                plo[w][quad * 4 + reg][nt * 16 + l15] = bf16_rne(p[nt] - bf16_tof(hi));
            }
        }

        // ---- P A-frags from LDS (per-wave slab: DS in-order, no barrier) ----
        bf16x8 ph[2], pl[2];
        #pragma unroll
        for (int kc2 = 0; kc2 < 2; ++kc2) {
            ph[kc2] = *(const bf16x8*)&phi[w][l15][kc2 * 32 + quad * 8];
            pl[kc2] = *(const bf16x8*)&plo[w][l15][kc2 * 32 + quad * 8];
        }

        // ---- O += P V ----
        #pragma unroll
        for (int dt = 0; dt < 4; ++dt) {
            f32x4 a = O[dt];
            a = __builtin_amdgcn_mfma_f32_16x16x32_bf16(ph[0], vh0[dt], a, 0, 0, 0);
            a = __builtin_amdgcn_mfma_f32_16x16x32_bf16(ph[1], vh1[dt], a, 0, 0, 0);
            a = __builtin_amdgcn_mfma_f32_16x16x32_bf16(ph[0], vl0[dt], a, 0, 0, 0);
            a = __builtin_amdgcn_mfma_f32_16x16x32_bf16(ph[1], vl1[dt], a, 0, 0, 0);
            a = __builtin_amdgcn_mfma_f32_16x16x32_bf16(pl[0], vh0[dt], a, 0, 0, 0);
            a = __builtin_amdgcn_mfma_f32_16x16x32_bf16(pl[1], vh1[dt], a, 0, 0, 0);
            O[dt] = a;
        }

        // ---- gather next tile's delta (eid prefetch has landed) ----
        if (more) {
            #pragma unroll
            for (int i = 0; i < 16; ++i) {
                int e = enxt[i];
                float d = 0.f;
                if (e >= 0) d = delta8[(size_t)e * Hh + h];   // exec-masked gather
                dcur[i] = d;
            }
            #pragma unroll
            for (int nt = 0; nt < 4; ++nt) kvcur[nt] = kvnxt[nt];
        }
    }

    // ---- one deferred row-sum reduction (within each quad's 16 lanes) ----
    #pragma unroll
    for (int reg = 0; reg < 4; ++reg) {
        #pragma unroll
        for (int o = 1; o < 16; o <<= 1) lsum[reg] += __shfl_xor(lsum[reg], o);
    }

    // ---- store partials ----
    #pragma unroll
    for (int dt = 0; dt < 4; ++dt)
        #pragma unroll
        for (int reg = 0; reg < 4; ++reg)
            Opart[((size_t)(s * Hh + h) * Nn + q0 + quad * 4 + reg) * 64 + dt * 16 + l15] = O[dt][reg];
    if (l15 == 0) {
        #pragma unroll
        for (int reg = 0; reg < 4; ++reg)
            Lpart[(size_t)(s * Hh + h) * Nn + q0 + quad * 4 + reg] = lsum[reg];
    }
}

// ------------- split-K combine (plain sums) fused with maxpool s1 -----------
__global__ __launch_bounds__(256) void combine_mp_k(
    const float* __restrict__ Opart, const float* __restrict__ Lpart,
    float* __restrict__ partial)
{
    const int b = blockIdx.x;            // 384 blocks, 4 q-rows each
    const int t = threadIdx.x;
    const int cg = (t & 127) * 4;
    const int h = cg >> 6, d = cg & 63;
    const int rh = t >> 7;
    f4 mx = {-3.0e38f, -3.0e38f, -3.0e38f, -3.0e38f};
    for (int r = 0; r < 2; ++r) {
        int q = b * 4 + rh * 2 + r;
        float l = 0.f;
        f4 o = {0.f, 0.f, 0.f, 0.f};
        #pragma unroll
        for (int s2 = 0; s2 < SPLITS; ++s2) {
            l += Lpart[(size_t)(s2 * Hh + h) * Nn + q];
            f4 ov = *(const f4*)(Opart + ((size_t)(s2 * Hh + h) * Nn + q) * 64 + d);
            #pragma unroll
            for (int c = 0; c < 4; ++c) o[c] += ov[c];
        }
        float inv = 1.0f / l;
        #pragma unroll
        for (int c = 0; c < 4; ++c) mx[c] = fmaxf(mx[c], o[c] * inv);
    }
    *(f4*)(partial + (size_t)(b * 2 + rh) * 512 + cg) = mx;
}

// -------------------- two-stage final maxpool (768 -> 32 -> 1) --------------
__global__ __launch_bounds__(128) void mp2a_k(const float* __restrict__ partial,
                                              float* __restrict__ partial2)
{
    const int b = blockIdx.x;            // 32
    const int t = threadIdx.x;
    f4 mx = {-3.0e38f, -3.0e38f, -3.0e38f, -3.0e38f};
    for (int i = 0; i < 24; ++i) {
        f4 v = *(const f4*)(partial + (size_t)(b * 24 + i) * 512 + 4 * t);
        #pragma unroll
        for (int c = 0; c < 4; ++c) mx[c] = fmaxf(mx[c], v[c]);
    }
    *(f4*)(partial2 + (size_t)b * 512 + 4 * t) = mx;
}

__global__ __launch_bounds__(128) void mp2b_k(const float* __restrict__ partial2,
                                              float* __restrict__ outp)
{
    const int t = threadIdx.x;
    f4 mx = {-3.0e38f, -3.0e38f, -3.0e38f, -3.0e38f};
    for (int b = 0; b < 32; ++b) {
        f4 v = *(const f4*)(partial2 + (size_t)b * 512 + 4 * t);
        #pragma unroll
        for (int c = 0; c < 4; ++c) mx[c] = fmaxf(mx[c], v[c]);
    }
    *(f4*)(outp + 4 * t) = mx;
}

// ---------------------------------------------------------------------------
extern "C" void kernel_launch(void* const* d_in, const int* in_sizes, int n_in,
                              void* d_out, int out_size, void* d_ws, size_t ws_size,
                              hipStream_t stream)
{
    const float* feat   = (const float*)d_in[0];
    const int*   rawidx = (const int*)d_in[1];
    const float* attr   = (const float*)d_in[2];
    const float* Wq = (const float*)d_in[4];
    const float* bq = (const float*)d_in[5];
    const float* Wk = (const float*)d_in[6];
    const float* bk = (const float*)d_in[7];
    const float* Wv = (const float*)d_in[8];
    const float* bv = (const float*)d_in[9];
    float* outp = (float*)d_out;
    const int E = in_sizes[2];

    const size_t ND_ = (size_t)Nn * Dd;            // 786432
    const size_t NN_ = (size_t)Nn * Nn;            // 2359296
    const size_t PK_ = (size_t)Hh * 96 * 2 * 512;  // 786432 bf16 per pack array

    // Layout: regions dead by flash6 time come FIRST and contiguously:
    //   Q,K,V (2359296 f) | rel (2359296 f) | pFh,pFl,pWh,pWl (1572864 f-equiv)
    //   = 6291456 floats  ==  Opart at SPLITS=8 (8*8*1536*64)  -- exact alias.
    // eid (live during flash) starts right after the aliased region.
    float* ws    = (float*)d_ws;
    float* Q     = ws;                    // 786432
    float* K     = Q + ND_;               // 786432
    float* V     = K + ND_;               // 786432
    float* rel   = V + ND_;               // 2359296
    unsigned short* pFh = (unsigned short*)(rel + NN_);   // feat/W packs (dead by flash)
    unsigned short* pFl = pFh + PK_;
    unsigned short* pWh = pFl + PK_;
    unsigned short* pWl = pWh + PK_;
    int*   eid   = (int*)(pWl + PK_);     // 2359296 (LIVE during flash)
    float* delta8 = (float*)(eid + NN_);  // E*Hh = 393216
    float* qodd  = delta8 + (size_t)E * Hh;
    float* kodd  = qodd + (size_t)Nn * Hh;
    float* koddT = kodd + (size_t)Nn * Hh;
    int*   idxn  = (int*)(koddT + (size_t)Nn * Hh);
    unsigned short* pQh = (unsigned short*)(idxn + 2 * E);
    unsigned short* pQl = pQh + PK_;
    unsigned short* pKh = pQl + PK_;
    unsigned short* pKl = pKh + PK_;
    unsigned short* pVh = pKl + PK_;
    unsigned short* pVl = pVh + PK_;
    float* Lpart = (float*)(pVl + PK_);                    // SPLITS*Hh*Nn = 98304
    float* partial = Lpart + (size_t)SPLITS * Hh * Nn;     // 768*512
    float* partial2 = partial + (size_t)768 * 512;         // 32*512
    // Opart (SPLITS*Hh*Nn*64 = 6291456 floats) aliases Q,K,V + rel + pF/pW:
    // all dead by flash6 time (flash reads only pQ..pVl/eid/delta8/koddT).
    float* Opart = ws;

    pack_fw_k<<<dim3(384, 2), 256, 0, stream>>>(feat, Wq, Wk, Wv, pFh, pFl, pWh, pWl);
    qkvm_k<<<dim3(8, 24, 3), 256, 0, stream>>>(pFh, pFl, pWh, pWl, bq, bk, bv, Q, K, V);
    init_rel_k<<<(int)((NN_ / 4 + 255) / 256), 256, 0, stream>>>(rel, eid);
    scatter_k<<<(E + 255) / 256, 256, 0, stream>>>(rawidx, attr, rel, eid, idxn, E);
    oddsum_k<<<(2 * Nn * Hh + 255) / 256, 256, 0, stream>>>(Q, K, qodd, kodd, koddT);
    delta2_k<<<(E + 3) / 4, 256, 0, stream>>>(idxn, rel, Q, K, qodd, kodd, delta8, E);
    pack_k<<<dim3(384, 3), 256, 0, stream>>>(Q, K, V, pQh, pQl, pKh, pKl, pVh, pVl);
    flash6_k<<<dim3(24, 8, SPLITS), 256, 0, stream>>>(pQh, pQl, pKh, pKl, pVh, pVl,
                                                      eid, delta8, koddT, Opart, Lpart);
    combine_mp_k<<<384, 256, 0, stream>>>(Opart, Lpart, partial);
    mp2a_k<<<32, 128, 0, stream>>>(partial, partial2);
    mp2b_k<<<1, 128, 0, stream>>>(partial2, outp);
}